// Round 5
// baseline (782.313 us; speedup 1.0000x reference)
//
#include <hip/hip_runtime.h>

#define HID 512
#define SLEN 4096
#define NB 8
#define BSROWS (NB*SLEN)     // 32768 rows per direction
#define NLAYER 4
#define CHUNKT 256
#define NCHUNK 16

typedef float f32x4 __attribute__((ext_vector_type(4)));
typedef unsigned int u32x4 __attribute__((ext_vector_type(4)));

typedef const __attribute__((address_space(1))) unsigned int* gas_u32p;
typedef __attribute__((address_space(3))) unsigned int* las_u32p;

__device__ __forceinline__ float bf2f(unsigned short u){
  union { unsigned int i; float f; } v; v.i = ((unsigned int)u) << 16; return v.f;
}
__device__ __forceinline__ unsigned short f2bf(float f){
  union { float f; unsigned int i; } v; v.f = f;
  unsigned int u = v.i;
  u = u + 0x7fffu + ((u >> 16) & 1u);
  return (unsigned short)(u >> 16);
}
__device__ __forceinline__ void mfma_bf16(f32x4& acc, u32x4 a, u32x4 b){
  asm("v_mfma_f32_16x16x32_bf16 %0, %1, %2, %0" : "+v"(acc) : "v"(a), "v"(b));
}
// MFMA D-write -> VALU read hazard fence (inline asm is opaque to the
// hazard recognizer; CDNA has no HW interlock here).
__device__ __forceinline__ void mfma_fence(){
  __builtin_amdgcn_sched_barrier(0);
  asm volatile("s_nop 7\n\ts_nop 7\n\ts_nop 7\n\ts_nop 7");
  __builtin_amdgcn_sched_barrier(0);
}
__device__ __forceinline__ void decode_ab(unsigned int v, float& a, float& b){
  a = (float)(v & 0xffffu) * (1.f/65535.f);
  b = fmaf((float)(v >> 16), 2.f/65535.f, -1.f);
}
__device__ __forceinline__ void gload_lds16(const unsigned short* g, unsigned short* l){
  __builtin_amdgcn_global_load_lds((gas_u32p)(const void*)g, (las_u32p)(void*)l, 16, 0, 0);
}
// scan-LDS index with bank-conflict-breaking band swizzle
__device__ __forceinline__ int scidx(int row, int col){
  return row*64 + (col ^ (((row>>2)&3)<<4));
}

// ---------------- prep kernels ----------------

__global__ __launch_bounds__(256) void prep_w(
    const float* __restrict__ wzf, const float* __restrict__ whf,
    const float* __restrict__ wzb, const float* __restrict__ whb,
    unsigned short* __restrict__ wbf)
{
  int idx = blockIdx.x*256 + threadIdx.x;   // 524288 total
  int i8  = idx & 63;
  int o   = (idx >> 6) & 511;
  int m   = (idx >> 15) & 1;
  int l   = (idx >> 16) & 3;
  int dir = idx >> 18;
  const float* src = dir ? (m ? whb : wzb) : (m ? whf : wzf);
  const float* p = src + ((size_t)(l*512 + o)*512 + i8*8);
  float4 v0 = *(const float4*)p;
  float4 v1 = *(const float4*)(p+4);
  unsigned short* q = wbf + ((((size_t)(dir*4 + l)*2 + m)*512 + o)*512 + i8*8);
  u32x4 outv;
  outv[0] = (unsigned)f2bf(v0.x) | ((unsigned)f2bf(v0.y)<<16);
  outv[1] = (unsigned)f2bf(v0.z) | ((unsigned)f2bf(v0.w)<<16);
  outv[2] = (unsigned)f2bf(v1.x) | ((unsigned)f2bf(v1.y)<<16);
  outv[3] = (unsigned)f2bf(v1.z) | ((unsigned)f2bf(v1.w)<<16);
  *(u32x4*)q = outv;
}

__global__ __launch_bounds__(256) void prep_fw(
    const float* __restrict__ fw, unsigned short* __restrict__ outw)
{
  int idx = blockIdx.x*256 + threadIdx.x;   // 65536
  const float* p = fw + (size_t)idx*8;
  float4 v0 = *(const float4*)p;
  float4 v1 = *(const float4*)(p+4);
  u32x4 outv;
  outv[0] = (unsigned)f2bf(v0.x) | ((unsigned)f2bf(v0.y)<<16);
  outv[1] = (unsigned)f2bf(v0.z) | ((unsigned)f2bf(v0.w)<<16);
  outv[2] = (unsigned)f2bf(v1.x) | ((unsigned)f2bf(v1.y)<<16);
  outv[3] = (unsigned)f2bf(v1.z) | ((unsigned)f2bf(v1.w)<<16);
  *(u32x4*)(outw + (size_t)idx*8) = outv;
}

__global__ __launch_bounds__(256) void prep_x(
    const float* __restrict__ x, unsigned short* __restrict__ X0)
{
  int idx = blockIdx.x*256 + threadIdx.x;   // 4194304
  int j8  = idx & 63;
  int s   = (idx >> 6) & 4095;
  int b   = (idx >> 18) & 7;
  int dir = idx >> 21;
  int srcs = dir ? (4095 - s) : s;
  const float* p = x + ((size_t)(b*SLEN + srcs)*512 + j8*8);
  float4 v0 = *(const float4*)p;
  float4 v1 = *(const float4*)(p+4);
  u32x4 outv;
  outv[0] = (unsigned)f2bf(v0.x) | ((unsigned)f2bf(v0.y)<<16);
  outv[1] = (unsigned)f2bf(v0.z) | ((unsigned)f2bf(v0.w)<<16);
  outv[2] = (unsigned)f2bf(v1.x) | ((unsigned)f2bf(v1.y)<<16);
  outv[3] = (unsigned)f2bf(v1.z) | ((unsigned)f2bf(v1.w)<<16);
  *(u32x4*)(X0 + ((size_t)((dir*NB + b)*SLEN + s)*512 + j8*8)) = outv;
}

// ---------------- gate GEMM + in-block chunk scan ----------------
// Block: 256 thr (4 waves). Tile: 256 rows (== one scan chunk) x 64 h-cols.
// Wave owns 64 rows: 4 mf x 4 nf x {z,h} accumulators (128 acc VGPRs).
// Per kk: 4 A-reads + 8 B-reads per 32 MFMA = 0.375 KB/MFMA LDS demand.

__global__ __launch_bounds__(256, 2) void gate_gemm_scan(
    const unsigned short* __restrict__ X,    // group base [R][512] bf16
    const unsigned short* __restrict__ Wz,   // [512][512] bf16
    const unsigned short* __restrict__ Wh,
    const float* __restrict__ bzp, const float* __restrict__ bhp,  // [512]
    unsigned int* __restrict__ PH,           // [R][512] packed (P,h')
    float* __restrict__ Aagg, float* __restrict__ Bagg,
    int Mtiles, int CG)
{
  __shared__ __align__(16) unsigned char smem[65536 + 2048];
  unsigned short* As  = (unsigned short*)smem;              // [256][64] bf16
  unsigned short* Bzs = (unsigned short*)(smem + 32768);    // [64][64]
  unsigned short* Bhs = (unsigned short*)(smem + 40960);    // [64][64]
  unsigned int*   SC  = (unsigned int*)smem;                // [256][64] u32 (alias)
  float* SegP = (float*)(smem + 65536);                     // [4][64]
  float* SegH = (float*)(smem + 65536 + 1024);              // [4][64]

  int hw = blockIdx.x;
  int lg = (hw & 7)*Mtiles + (hw >> 3);     // XCD-chunked swizzle (grid = 8*Mtiles)
  int nt  = lg & 7;
  int mt  = lg >> 3;

  const int tid = threadIdx.x;
  const int lane = tid & 63;
  const int wv = tid >> 6;
  const int n0 = nt*64;
  const int slot = tid & 7;
  const int rowb = tid >> 3;

  f32x4 accz[4][4], acch[4][4];
  #pragma unroll
  for (int i=0;i<4;++i)
    #pragma unroll
    for (int j=0;j<4;++j){ accz[i][j] = (f32x4)(0.f); acch[i][j] = (f32x4)(0.f); }

  for (int ks=0; ks<8; ++ks){
    int k0 = ks*64;
    #pragma unroll
    for (int it=0; it<8; ++it){
      int row = rowb + it*32;
      u32x4 v = *(const u32x4*)(X + (size_t)(mt*256+row)*512 + k0 + slot*8);
      *(u32x4*)(As + row*64 + ((slot ^ (row&7))<<3)) = v;
    }
    #pragma unroll
    for (int it=0; it<2; ++it){
      int row = rowb + it*32;
      u32x4 vz = *(const u32x4*)(Wz + (size_t)(n0+row)*512 + k0 + slot*8);
      *(u32x4*)(Bzs + row*64 + ((slot ^ (row&7))<<3)) = vz;
      u32x4 vh = *(const u32x4*)(Wh + (size_t)(n0+row)*512 + k0 + slot*8);
      *(u32x4*)(Bhs + row*64 + ((slot ^ (row&7))<<3)) = vh;
    }
    __syncthreads();
    #pragma unroll
    for (int kk=0; kk<2; ++kk){
      int kslot = kk*4 + (lane >> 4);
      u32x4 af[4];
      #pragma unroll
      for (int mf=0; mf<4; ++mf){
        int row = wv*64 + mf*16 + (lane & 15);
        af[mf] = *(const u32x4*)(As + row*64 + ((kslot ^ (row&7))<<3));
      }
      #pragma unroll
      for (int nf=0; nf<4; ++nf){
        int row = nf*16 + (lane & 15);
        u32x4 bz = *(const u32x4*)(Bzs + row*64 + ((kslot ^ (row&7))<<3));
        u32x4 bh = *(const u32x4*)(Bhs + row*64 + ((kslot ^ (row&7))<<3));
        #pragma unroll
        for (int mf=0; mf<4; ++mf){
          mfma_bf16(accz[mf][nf], af[mf], bz);
          mfma_bf16(acch[mf][nf], af[mf], bh);
        }
      }
    }
    __syncthreads();
  }
  mfma_fence();

  // ---- epilogue: gates -> packed fixed-point (a,b) into LDS (band-swizzled) ----
  #pragma unroll
  for (int nf=0; nf<4; ++nf){
    int colL = nf*16 + (lane & 15);
    float bz = bzp[n0 + colL];
    float bh = bhp[n0 + colL];
    #pragma unroll
    for (int mf=0; mf<4; ++mf){
      int rloc = wv*64 + mf*16 + ((lane>>4)<<2);
      #pragma unroll
      for (int r=0; r<4; ++r){
        float zp = accz[mf][nf][r] + bz;
        float hp = acch[mf][nf][r] + bh;
        float sg = 1.f/(1.f + __expf(-zp));
        float th = 1.f - 2.f/(1.f + __expf(2.f*hp));
        float a = 1.f - sg;
        a = fminf(fmaxf(a, 1e-8f), 1.0f);   // ref clip hi = 1-1e-8, rounds to 1.0f
        float bv = sg*th;                    // |bv| < 1
        unsigned aq = (unsigned)fmaf(a, 65535.f, 0.5f);
        unsigned bq = (unsigned)fmaf(bv, 32767.5f, 32768.0f);
        SC[scidx(rloc + r, colL)] = aq | (bq << 16);
      }
    }
  }
  __syncthreads();

  // ---- pass 1: per-segment local scan (in-place LDS rewrite) ----
  const int col = tid & 63;
  const int seg = tid >> 6;       // == wave id, uniform per wave
  float P = 1.f, Hl = 0.f;
  #pragma unroll 8
  for (int r=0; r<64; ++r){
    int row = seg*64 + r;
    float a, b; decode_ab(SC[scidx(row, col)], a, b);
    Hl = fmaf(a, Hl, b);
    P *= a;
    unsigned pq = (unsigned)fmaf(P, 65535.f, 0.5f);
    SC[scidx(row, col)] = pq | ((unsigned)f2bf(Hl) << 16);
  }
  SegP[seg*64 + col] = P;
  SegH[seg*64 + col] = Hl;
  __syncthreads();

  // ---- segment prefixes (<=3 serial combines, wave-uniform trip count) ----
  float Ppre = 1.f, Hpre = 0.f;
  for (int j=0; j<seg; ++j){
    Hpre = fmaf(SegP[j*64 + col], Hpre, SegH[j*64 + col]);
    Ppre *= SegP[j*64 + col];
  }

  // ---- pass 2: apply prefix, write per-token (P,h') + chunk aggregates ----
  const int rowbase = mt*256;
  float Pg = 1.f, Hg = 0.f;
  #pragma unroll 8
  for (int r=0; r<64; ++r){
    int row = seg*64 + r;
    unsigned v = SC[scidx(row, col)];
    float Pl = (float)(v & 0xffffu) * (1.f/65535.f);
    float Hlv = bf2f((unsigned short)(v >> 16));
    Pg = Ppre * Pl;
    Hg = fmaf(Pl, Hpre, Hlv);
    unsigned pq = (unsigned)fmaf(Pg, 65535.f, 0.5f);
    PH[(size_t)(rowbase + row)*512 + n0 + col] = pq | ((unsigned)f2bf(Hg) << 16);
  }
  if (seg == 3){
    int chain = (mt >> 4)*512 + n0 + col;   // batch-in-group * 512 + h
    int c = mt & 15;                        // chunk within sequence (4096/256=16)
    Aagg[c*CG + chain] = Pg;
    Bagg[c*CG + chain] = Hg;
  }
}

// ---------------- cross-chunk combine (tiny) ----------------

__global__ __launch_bounds__(256) void scan_p2(
    const float* __restrict__ Aagg, const float* __restrict__ Bagg,
    float* __restrict__ Hin, int CG)
{
  int chain = blockIdx.x*256 + threadIdx.x;  // CG threads
  float hv = 0.f;
  #pragma unroll
  for (int c=0; c<NCHUNK; ++c){
    Hin[c*CG + chain] = hv;
    hv = fmaf(Aagg[c*CG + chain], hv, Bagg[c*CG + chain]);
  }
}

// ---------------- h reconstruction + residual + LayerNorm (in-place X) ----------------

__global__ __launch_bounds__(256) void recon_ln(
    const unsigned int* __restrict__ PH,     // group [R][512]
    const float* __restrict__ Hin,           // [16][CG]
    unsigned short* __restrict__ Xio,        // group [R][512] bf16 in/out
    const float* __restrict__ g, const float* __restrict__ bta,
    int resid, int CG)
{
  int token = blockIdx.x*4 + (threadIdx.x >> 6);
  int lane = threadIdx.x & 63;
  size_t base = (size_t)token*512 + lane*8;
  u32x4 p0 = *(const u32x4*)(PH + base);
  u32x4 p1 = *(const u32x4*)(PH + base + 4);
  int c  = (token >> 8) & 15;
  int bl = token >> 12;
  const float* hin = Hin + (size_t)c*CG + bl*512 + lane*8;
  f32x4 h0 = *(const f32x4*)hin;
  f32x4 h1 = *(const f32x4*)(hin + 4);
  float v[8];
  #pragma unroll
  for (int j=0; j<4; ++j){
    v[j]   = fmaf((float)(p0[j] & 0xffffu)*(1.f/65535.f), h0[j], bf2f((unsigned short)(p0[j] >> 16)));
    v[4+j] = fmaf((float)(p1[j] & 0xffffu)*(1.f/65535.f), h1[j], bf2f((unsigned short)(p1[j] >> 16)));
  }
  if (resid){
    u32x4 xv = *(const u32x4*)(Xio + base);
    #pragma unroll
    for (int w=0; w<4; ++w){
      v[2*w]   += bf2f((unsigned short)(xv[w] & 0xffffu));
      v[2*w+1] += bf2f((unsigned short)(xv[w] >> 16));
    }
  }
  float s = 0.f, s2 = 0.f;
  #pragma unroll
  for (int j=0; j<8; ++j){ s += v[j]; s2 += v[j]*v[j]; }
  #pragma unroll
  for (int o=1; o<64; o<<=1){ s += __shfl_xor(s, o, 64); s2 += __shfl_xor(s2, o, 64); }
  float mu = s * (1.f/512.f);
  float var = s2 * (1.f/512.f) - mu*mu;
  float inv = rsqrtf(var + 1e-5f);
  float4 g0 = *(const float4*)(g + lane*8);
  float4 g1 = *(const float4*)(g + lane*8 + 4);
  float4 b0 = *(const float4*)(bta + lane*8);
  float4 b1 = *(const float4*)(bta + lane*8 + 4);
  float gg[8]  = {g0.x,g0.y,g0.z,g0.w,g1.x,g1.y,g1.z,g1.w};
  float bbv[8] = {b0.x,b0.y,b0.z,b0.w,b1.x,b1.y,b1.z,b1.w};
  u32x4 outv;
  #pragma unroll
  for (int w=0; w<4; ++w){
    float y0 = (v[2*w]   - mu)*inv*gg[2*w]   + bbv[2*w];
    float y1 = (v[2*w+1] - mu)*inv*gg[2*w+1] + bbv[2*w+1];
    outv[w] = (unsigned)f2bf(y0) | ((unsigned)f2bf(y1) << 16);
  }
  *(u32x4*)(Xio + base) = outv;
}

// ---------------- fusion GEMM: out = [fwd, flip(bwd)] @ Wf^T + fb ----------------
// 256-row tile, wave = 64 rows (4 mf x 4 nf), gload_lds staging.

__global__ __launch_bounds__(256, 2) void fusion_gemm(
    const unsigned short* __restrict__ Xf,   // [2*BSROWS][512] final LN outputs
    const unsigned short* __restrict__ Wf,   // [512][1024] bf16
    const float* __restrict__ fb,
    float* __restrict__ outp)
{
  __shared__ __align__(16) unsigned short As[256*64];   // 32 KiB
  __shared__ __align__(16) unsigned short Bs[64*64];    // 8 KiB

  int hw = blockIdx.x;
  int lg = (hw & 7)*128 + (hw >> 3);   // 1024 blocks
  int nt = lg & 7;
  int mt = lg >> 3;                    // 0..127

  const int tid = threadIdx.x;
  const int lane = tid & 63;
  const int wv = tid >> 6;
  const int n0 = nt*64;
  const int lrow  = lane >> 3;
  const int slotp = (lane & 7) ^ (lrow & 7);

  f32x4 acc[4][4];
  #pragma unroll
  for (int i=0;i<4;++i)
    #pragma unroll
    for (int j=0;j<4;++j) acc[i][j] = (f32x4)(0.f);

  for (int ks=0; ks<16; ++ks){
    int k0 = ks*64;
    const unsigned short* Abase = Xf + ((k0 >= 512) ? (size_t)BSROWS*512 : 0);
    int kc = k0 & 511;
    int flip = (k0 >= 512) ? 4095 : 0;
    #pragma unroll
    for (int it=0; it<8; ++it){
      int row = it*32 + wv*8 + lrow;
      int sr = (mt*256 + row) ^ flip;        // flip s within batch for bwd half
      gload_lds16(Abase + (size_t)sr*512 + kc + slotp*8,
                  As + (it*32 + wv*8)*64);
    }
    #pragma unroll
    for (int it=0; it<2; ++it){
      int row = it*32 + wv*8 + lrow;
      gload_lds16(Wf + (size_t)(n0 + row)*1024 + k0 + slotp*8,
                  Bs + (it*32 + wv*8)*64);
    }
    __syncthreads();
    #pragma unroll
    for (int kk=0; kk<2; ++kk){
      int kslot = kk*4 + (lane >> 4);
      u32x4 af[4];
      #pragma unroll
      for (int mf=0; mf<4; ++mf){
        int row = wv*64 + mf*16 + (lane & 15);
        af[mf] = *(const u32x4*)(As + row*64 + ((kslot ^ (row&7))<<3));
      }
      #pragma unroll
      for (int nf=0; nf<4; ++nf){
        int row = nf*16 + (lane & 15);
        u32x4 bv = *(const u32x4*)(Bs + row*64 + ((kslot ^ (row&7))<<3));
        #pragma unroll
        for (int mf=0; mf<4; ++mf) mfma_bf16(acc[mf][nf], af[mf], bv);
      }
    }
    __syncthreads();
  }
  mfma_fence();

  #pragma unroll
  for (int nf=0; nf<4; ++nf){
    int col = n0 + nf*16 + (lane & 15);
    float bias = fb[col];
    #pragma unroll
    for (int mf=0; mf<4; ++mf){
      int rb = mt*256 + wv*64 + mf*16 + ((lane>>4)<<2);
      #pragma unroll
      for (int r=0; r<4; ++r)
        outp[(size_t)(rb + r)*512 + col] = acc[mf][nf][r] + bias;
    }
  }
}

// ---------------- launch ----------------

extern "C" void kernel_launch(void* const* d_in, const int* in_sizes, int n_in,
                              void* d_out, int out_size, void* d_ws, size_t ws_size,
                              hipStream_t stream)
{
  (void)in_sizes; (void)n_in; (void)out_size;
  const float* x   = (const float*)d_in[0];
  const float* wzf = (const float*)d_in[1];
  const float* bzf = (const float*)d_in[2];
  const float* whf = (const float*)d_in[3];
  const float* bhf = (const float*)d_in[4];
  const float* wzb = (const float*)d_in[5];
  const float* bzb = (const float*)d_in[6];
  const float* whb = (const float*)d_in[7];
  const float* bhb = (const float*)d_in[8];
  const float* fw  = (const float*)d_in[9];
  const float* fbb = (const float*)d_in[10];
  const float* lng = (const float*)d_in[11];
  const float* lnb = (const float*)d_in[12];
  float* outp = (float*)d_out;

  // Pick the largest per-direction batch-group count SG that fits ws_size.
  const size_t WbfB = (size_t)16*512*512*2;        // 8 MiB
  const size_t WfbB = (size_t)512*1024*2;          // 1 MiB
  const size_t XB   = (size_t)2*BSROWS*512*2;      // 64 MiB
  const size_t aggB = (size_t)4096*NCHUNK*4;       // 256 KiB (max CG)
  int SG = 8;
  for (int c = 1; c <= 8; c <<= 1){
    size_t need = WbfB + WfbB + XB + 3*aggB
                + ((size_t)BSROWS/c)*512*4          // PH
                + 1024;
    if (need <= ws_size){ SG = c; break; }
  }
  const int R  = BSROWS / SG;      // rows per group
  const int NBg = NB / SG;         // batches per group
  const int CG = NBg * 512;        // scan chains per group
  const int Mtiles = R / 256;

  char* ws = (char*)d_ws;
  size_t o = 0;
  unsigned short* Wbf = (unsigned short*)(ws + o); o += WbfB;
  unsigned short* Wfb = (unsigned short*)(ws + o); o += WfbB;
  unsigned short* X   = (unsigned short*)(ws + o); o += XB;
  unsigned int*   PH  = (unsigned int*)  (ws + o); o += (size_t)R*512*4;
  float* Aagg = (float*)(ws + o); o += aggB;
  float* Bagg = (float*)(ws + o); o += aggB;
  float* Hin  = (float*)(ws + o); o += aggB;

  prep_w <<<2048, 256, 0, stream>>>(wzf, whf, wzb, whb, Wbf);
  prep_fw<<<256,  256, 0, stream>>>(fw, Wfb);
  prep_x <<<16384,256, 0, stream>>>(x, X);

  for (int dir = 0; dir < 2; ++dir){
    const float* bz = dir ? bzb : bzf;
    const float* bh = dir ? bhb : bhf;
    for (int g = 0; g < SG; ++g){
      unsigned short* Xg = X + ((size_t)dir*BSROWS + (size_t)g*R)*512;
      for (int l = 0; l < NLAYER; ++l){
        const unsigned short* Wz = Wbf + ((size_t)((dir*4 + l)*2 + 0))*(512*512);
        const unsigned short* Wh = Wbf + ((size_t)((dir*4 + l)*2 + 1))*(512*512);
        gate_gemm_scan<<<Mtiles*8, 256, 0, stream>>>(Xg, Wz, Wh, bz + l*512, bh + l*512,
                                                     PH, Aagg, Bagg, Mtiles, CG);
        scan_p2 <<<CG/256, 256, 0, stream>>>(Aagg, Bagg, Hin, CG);
        recon_ln<<<R/4,    256, 0, stream>>>(PH, Hin, Xg, lng, lnb, l > 0 ? 1 : 0, CG);
      }
    }
  }
  fusion_gemm<<<1024, 256, 0, stream>>>(X, Wfb, fbb, outp);
}

// Round 7
// 700.825 us; speedup vs baseline: 1.1163x; 1.1163x over previous
//
#include <hip/hip_runtime.h>

#define HID 512
#define SLEN 4096
#define NB 8
#define BSROWS (NB*SLEN)     // 32768 rows per direction
#define NLAYER 4
#define CHUNKT 128
#define NCHUNK 32

typedef float f32x4 __attribute__((ext_vector_type(4)));
typedef unsigned int u32x4 __attribute__((ext_vector_type(4)));

typedef const __attribute__((address_space(1))) unsigned int* gas_u32p;
typedef __attribute__((address_space(3))) unsigned int* las_u32p;

__device__ __forceinline__ float bf2f(unsigned short u){
  union { unsigned int i; float f; } v; v.i = ((unsigned int)u) << 16; return v.f;
}
__device__ __forceinline__ unsigned short f2bf(float f){
  union { float f; unsigned int i; } v; v.f = f;
  unsigned int u = v.i;
  u = u + 0x7fffu + ((u >> 16) & 1u);
  return (unsigned short)(u >> 16);
}
__device__ __forceinline__ void mfma_bf16(f32x4& acc, u32x4 a, u32x4 b){
  asm("v_mfma_f32_16x16x32_bf16 %0, %1, %2, %0" : "+v"(acc) : "v"(a), "v"(b));
}
// MFMA D-write -> VALU read hazard fence (inline asm is opaque to the
// hazard recognizer; CDNA has no HW interlock here).
__device__ __forceinline__ void mfma_fence(){
  __builtin_amdgcn_sched_barrier(0);
  asm volatile("s_nop 7\n\ts_nop 7\n\ts_nop 7\n\ts_nop 7");
  __builtin_amdgcn_sched_barrier(0);
}
__device__ __forceinline__ void decode_ab(unsigned int v, float& a, float& b){
  a = (float)(v & 0xffffu) * (1.f/65535.f);
  b = fmaf((float)(v >> 16), 2.f/65535.f, -1.f);
}
__device__ __forceinline__ void gload_lds16(const unsigned short* g, unsigned short* l){
  __builtin_amdgcn_global_load_lds((gas_u32p)(const void*)g, (las_u32p)(void*)l, 16, 0, 0);
}
// scan-LDS index with bank-conflict-breaking band swizzle
__device__ __forceinline__ int scidx(int row, int col){
  return row*64 + (col ^ (((row>>2)&3)<<4));
}

// ---------------- prep kernels ----------------

__global__ __launch_bounds__(256) void prep_w(
    const float* __restrict__ wzf, const float* __restrict__ whf,
    const float* __restrict__ wzb, const float* __restrict__ whb,
    unsigned short* __restrict__ wbf)
{
  int idx = blockIdx.x*256 + threadIdx.x;   // 524288 total
  int i8  = idx & 63;
  int o   = (idx >> 6) & 511;
  int m   = (idx >> 15) & 1;
  int l   = (idx >> 16) & 3;
  int dir = idx >> 18;
  const float* src = dir ? (m ? whb : wzb) : (m ? whf : wzf);
  const float* p = src + ((size_t)(l*512 + o)*512 + i8*8);
  float4 v0 = *(const float4*)p;
  float4 v1 = *(const float4*)(p+4);
  unsigned short* q = wbf + ((((size_t)(dir*4 + l)*2 + m)*512 + o)*512 + i8*8);
  u32x4 outv;
  outv[0] = (unsigned)f2bf(v0.x) | ((unsigned)f2bf(v0.y)<<16);
  outv[1] = (unsigned)f2bf(v0.z) | ((unsigned)f2bf(v0.w)<<16);
  outv[2] = (unsigned)f2bf(v1.x) | ((unsigned)f2bf(v1.y)<<16);
  outv[3] = (unsigned)f2bf(v1.z) | ((unsigned)f2bf(v1.w)<<16);
  *(u32x4*)q = outv;
}

__global__ __launch_bounds__(256) void prep_fw(
    const float* __restrict__ fw, unsigned short* __restrict__ outw)
{
  int idx = blockIdx.x*256 + threadIdx.x;   // 65536
  const float* p = fw + (size_t)idx*8;
  float4 v0 = *(const float4*)p;
  float4 v1 = *(const float4*)(p+4);
  u32x4 outv;
  outv[0] = (unsigned)f2bf(v0.x) | ((unsigned)f2bf(v0.y)<<16);
  outv[1] = (unsigned)f2bf(v0.z) | ((unsigned)f2bf(v0.w)<<16);
  outv[2] = (unsigned)f2bf(v1.x) | ((unsigned)f2bf(v1.y)<<16);
  outv[3] = (unsigned)f2bf(v1.z) | ((unsigned)f2bf(v1.w)<<16);
  *(u32x4*)(outw + (size_t)idx*8) = outv;
}

// forward direction only; backward layer-0 reads this buffer row-flipped
// (scheduled BEFORE dir-0 in-place processing overwrites it).
__global__ __launch_bounds__(256) void prep_x(
    const float* __restrict__ x, unsigned short* __restrict__ X0)
{
  int idx = blockIdx.x*256 + threadIdx.x;   // 2097152
  int j8  = idx & 63;
  int s   = (idx >> 6) & 4095;
  int b   = idx >> 18;
  const float* p = x + ((size_t)(b*SLEN + s)*512 + j8*8);
  float4 v0 = *(const float4*)p;
  float4 v1 = *(const float4*)(p+4);
  u32x4 outv;
  outv[0] = (unsigned)f2bf(v0.x) | ((unsigned)f2bf(v0.y)<<16);
  outv[1] = (unsigned)f2bf(v0.z) | ((unsigned)f2bf(v0.w)<<16);
  outv[2] = (unsigned)f2bf(v1.x) | ((unsigned)f2bf(v1.y)<<16);
  outv[3] = (unsigned)f2bf(v1.z) | ((unsigned)f2bf(v1.w)<<16);
  *(u32x4*)(X0 + ((size_t)(b*SLEN + s)*512 + j8*8)) = outv;
}

// ---------------- gate GEMM + in-block chunk scan ----------------
// Block: 256 thr (4 waves). Tile: 128 rows (== one scan chunk) x 64 h-cols.
// Reg-staged LDS (measured faster than gload_lds for this 8-step K loop).
// Tail: pass1 computes segment aggregates only (no LDS rewrite); pass2
// re-decodes (a,b), recomputes local scan with prefix fused, writes PH.

__global__ __launch_bounds__(256) void gate_gemm_scan(
    const unsigned short* __restrict__ X,    // A-panel base [R][512] bf16
    const unsigned short* __restrict__ Wz,   // [512][512] bf16
    const unsigned short* __restrict__ Wh,
    const float* __restrict__ bzp, const float* __restrict__ bhp,  // [512]
    unsigned int* __restrict__ PH,           // [R][512] packed (P,h')
    float* __restrict__ Aagg, float* __restrict__ Bagg,
    int Mtiles, int CG, int flip)
{
  __shared__ __align__(16) unsigned char smem[32768 + 2048];
  unsigned short* As  = (unsigned short*)smem;              // [128][64] bf16
  unsigned short* Bzs = (unsigned short*)(smem + 16384);    // [64][64]
  unsigned short* Bhs = (unsigned short*)(smem + 24576);    // [64][64]
  unsigned int*   SC  = (unsigned int*)smem;                // [128][64] u32 (alias)
  float* SegP = (float*)(smem + 32768);                     // [4][64]
  float* SegH = (float*)(smem + 32768 + 1024);              // [4][64]

  int hw = blockIdx.x;
  int lg = (hw & 7)*Mtiles + (hw >> 3);     // XCD-chunked swizzle (grid = 8*Mtiles)
  int nt  = lg & 7;
  int mt  = lg >> 3;

  const int tid = threadIdx.x;
  const int lane = tid & 63;
  const int wv = tid >> 6;
  const int n0 = nt*64;
  const int slot = tid & 7;
  const int rowb = tid >> 3;

  f32x4 accz[2][4], acch[2][4];
  #pragma unroll
  for (int i=0;i<2;++i)
    #pragma unroll
    for (int j=0;j<4;++j){ accz[i][j] = (f32x4)(0.f); acch[i][j] = (f32x4)(0.f); }

  for (int ks=0; ks<8; ++ks){
    int k0 = ks*64;
    #pragma unroll
    for (int it=0; it<4; ++it){
      int row = rowb + it*32;
      int sr = (mt*128 + row) ^ flip;     // batch-local row flip (dir1, layer0)
      u32x4 v = *(const u32x4*)(X + (size_t)sr*512 + k0 + slot*8);
      *(u32x4*)(As + row*64 + ((slot ^ (row&7))<<3)) = v;
    }
    #pragma unroll
    for (int it=0; it<2; ++it){
      int row = rowb + it*32;
      u32x4 vz = *(const u32x4*)(Wz + (size_t)(n0+row)*512 + k0 + slot*8);
      *(u32x4*)(Bzs + row*64 + ((slot ^ (row&7))<<3)) = vz;
      u32x4 vh = *(const u32x4*)(Wh + (size_t)(n0+row)*512 + k0 + slot*8);
      *(u32x4*)(Bhs + row*64 + ((slot ^ (row&7))<<3)) = vh;
    }
    __syncthreads();
    #pragma unroll
    for (int kk=0; kk<2; ++kk){
      int kslot = kk*4 + (lane >> 4);
      u32x4 af[2];
      #pragma unroll
      for (int mf=0; mf<2; ++mf){
        int row = wv*32 + mf*16 + (lane & 15);
        af[mf] = *(const u32x4*)(As + row*64 + ((kslot ^ (row&7))<<3));
      }
      #pragma unroll
      for (int nf=0; nf<4; ++nf){
        int row = nf*16 + (lane & 15);
        u32x4 bz = *(const u32x4*)(Bzs + row*64 + ((kslot ^ (row&7))<<3));
        u32x4 bh = *(const u32x4*)(Bhs + row*64 + ((kslot ^ (row&7))<<3));
        #pragma unroll
        for (int mf=0; mf<2; ++mf){
          mfma_bf16(accz[mf][nf], af[mf], bz);
          mfma_bf16(acch[mf][nf], af[mf], bh);
        }
      }
    }
    __syncthreads();
  }
  mfma_fence();

  // ---- epilogue: gates -> packed fixed-point (a,b) into LDS (band-swizzled) ----
  #pragma unroll
  for (int nf=0; nf<4; ++nf){
    int colL = nf*16 + (lane & 15);
    float bz = bzp[n0 + colL];
    float bh = bhp[n0 + colL];
    #pragma unroll
    for (int mf=0; mf<2; ++mf){
      int rloc = wv*32 + mf*16 + ((lane>>4)<<2);
      #pragma unroll
      for (int r=0; r<4; ++r){
        float zp = accz[mf][nf][r] + bz;
        float hp = acch[mf][nf][r] + bh;
        float sg = 1.f/(1.f + __expf(-zp));
        float th = 1.f - 2.f/(1.f + __expf(2.f*hp));
        float a = 1.f - sg;
        a = fminf(fmaxf(a, 1e-8f), 1.0f);   // ref clip hi = 1-1e-8, rounds to 1.0f
        float bv = sg*th;                    // |bv| < 1
        unsigned aq = (unsigned)fmaf(a, 65535.f, 0.5f);
        unsigned bq = (unsigned)fmaf(bv, 32767.5f, 32768.0f);
        SC[scidx(rloc + r, colL)] = aq | (bq << 16);
      }
    }
  }
  __syncthreads();

  // ---- pass 1: per-segment aggregates only (no LDS rewrite) ----
  const int col = tid & 63;
  const int seg = tid >> 6;       // == wave id, uniform per wave
  {
    float P = 1.f, Hl = 0.f;
    #pragma unroll 8
    for (int r=0; r<32; ++r){
      float a, b; decode_ab(SC[scidx(seg*32 + r, col)], a, b);
      Hl = fmaf(a, Hl, b);
      P *= a;
    }
    SegP[seg*64 + col] = P;
    SegH[seg*64 + col] = Hl;
  }
  __syncthreads();

  // ---- segment prefixes (<=3 serial combines, wave-uniform trip count) ----
  float Ppre = 1.f, Hpre = 0.f;
  for (int j=0; j<seg; ++j){
    Hpre = fmaf(SegP[j*64 + col], Hpre, SegH[j*64 + col]);
    Ppre *= SegP[j*64 + col];
  }

  // ---- pass 2: recompute local scan, fuse prefix, write (P,h') + aggregates ----
  const int rowbase = mt*128;
  float pl = 1.f, hl = 0.f;
  float Pg = 1.f, Hg = 0.f;
  #pragma unroll 8
  for (int r=0; r<32; ++r){
    int row = seg*32 + r;
    float a, b; decode_ab(SC[scidx(row, col)], a, b);
    hl = fmaf(a, hl, b);
    pl *= a;
    Pg = Ppre * pl;
    Hg = fmaf(pl, Hpre, hl);
    unsigned pq = (unsigned)fmaf(Pg, 65535.f, 0.5f);
    PH[(size_t)(rowbase + row)*512 + n0 + col] = pq | ((unsigned)f2bf(Hg) << 16);
  }
  if (seg == 3){
    int chain = (mt >> 5)*512 + n0 + col;   // batch-in-group * 512 + h
    int c = mt & 31;                        // chunk within sequence
    Aagg[c*CG + chain] = Pg;
    Bagg[c*CG + chain] = Hg;
  }
}

// ---------------- cross-chunk combine (tiny) ----------------

__global__ __launch_bounds__(256) void scan_p2(
    const float* __restrict__ Aagg, const float* __restrict__ Bagg,
    float* __restrict__ Hin, int CG)
{
  int chain = blockIdx.x*256 + threadIdx.x;  // CG threads
  float hv = 0.f;
  #pragma unroll
  for (int c=0; c<NCHUNK; ++c){
    Hin[c*CG + chain] = hv;
    hv = fmaf(Aagg[c*CG + chain], hv, Bagg[c*CG + chain]);
  }
}

// ---------------- h reconstruction + residual + LayerNorm (in-place X) ----------------

__global__ __launch_bounds__(256) void recon_ln(
    const unsigned int* __restrict__ PH,     // group [R][512]
    const float* __restrict__ Hin,           // [32][CG]
    unsigned short* __restrict__ Xio,        // group [R][512] bf16 in/out
    const float* __restrict__ g, const float* __restrict__ bta,
    int resid, int CG)
{
  int token = blockIdx.x*4 + (threadIdx.x >> 6);
  int lane = threadIdx.x & 63;
  size_t base = (size_t)token*512 + lane*8;
  u32x4 p0 = *(const u32x4*)(PH + base);
  u32x4 p1 = *(const u32x4*)(PH + base + 4);
  int c  = (token >> 7) & 31;
  int bl = token >> 12;
  const float* hin = Hin + (size_t)c*CG + bl*512 + lane*8;
  f32x4 h0 = *(const f32x4*)hin;
  f32x4 h1 = *(const f32x4*)(hin + 4);
  float v[8];
  #pragma unroll
  for (int j=0; j<4; ++j){
    v[j]   = fmaf((float)(p0[j] & 0xffffu)*(1.f/65535.f), h0[j], bf2f((unsigned short)(p0[j] >> 16)));
    v[4+j] = fmaf((float)(p1[j] & 0xffffu)*(1.f/65535.f), h1[j], bf2f((unsigned short)(p1[j] >> 16)));
  }
  if (resid){
    u32x4 xv = *(const u32x4*)(Xio + base);
    #pragma unroll
    for (int w=0; w<4; ++w){
      v[2*w]   += bf2f((unsigned short)(xv[w] & 0xffffu));
      v[2*w+1] += bf2f((unsigned short)(xv[w] >> 16));
    }
  }
  float s = 0.f, s2 = 0.f;
  #pragma unroll
  for (int j=0; j<8; ++j){ s += v[j]; s2 += v[j]*v[j]; }
  #pragma unroll
  for (int o=1; o<64; o<<=1){ s += __shfl_xor(s, o, 64); s2 += __shfl_xor(s2, o, 64); }
  float mu = s * (1.f/512.f);
  float var = s2 * (1.f/512.f) - mu*mu;
  float inv = rsqrtf(var + 1e-5f);
  float4 g0 = *(const float4*)(g + lane*8);
  float4 g1 = *(const float4*)(g + lane*8 + 4);
  float4 b0 = *(const float4*)(bta + lane*8);
  float4 b1 = *(const float4*)(bta + lane*8 + 4);
  float gg[8]  = {g0.x,g0.y,g0.z,g0.w,g1.x,g1.y,g1.z,g1.w};
  float bbv[8] = {b0.x,b0.y,b0.z,b0.w,b1.x,b1.y,b1.z,b1.w};
  u32x4 outv;
  #pragma unroll
  for (int w=0; w<4; ++w){
    float y0 = (v[2*w]   - mu)*inv*gg[2*w]   + bbv[2*w];
    float y1 = (v[2*w+1] - mu)*inv*gg[2*w+1] + bbv[2*w+1];
    outv[w] = (unsigned)f2bf(y0) | ((unsigned)f2bf(y1) << 16);
  }
  *(u32x4*)(Xio + base) = outv;
}

// ---------------- fusion GEMM: out = [fwd, flip(bwd)] @ Wf^T + fb ----------------

__global__ __launch_bounds__(256) void fusion_gemm(
    const unsigned short* __restrict__ Xf,   // [2*BSROWS][512] final LN outputs
    const unsigned short* __restrict__ Wf,   // [512][1024] bf16
    const float* __restrict__ fb,
    float* __restrict__ outp)
{
  __shared__ __align__(16) unsigned short As[128*64];
  __shared__ __align__(16) unsigned short Bs[64*64];

  int hw = blockIdx.x;
  int lg = (hw & 7)*256 + (hw >> 3);   // 2048 blocks
  int nt = lg & 7;
  int mt = lg >> 3;                    // 0..255

  const int tid = threadIdx.x;
  const int lane = tid & 63;
  const int wv = tid >> 6;
  const int n0 = nt*64;
  const int lrow  = lane >> 3;
  const int slotp = (lane & 7) ^ (lrow & 7);

  f32x4 acc[2][4];
  #pragma unroll
  for (int i=0;i<2;++i)
    #pragma unroll
    for (int j=0;j<4;++j) acc[i][j] = (f32x4)(0.f);

  for (int ks=0; ks<16; ++ks){
    int k0 = ks*64;
    const unsigned short* Abase = Xf + ((k0 >= 512) ? (size_t)BSROWS*512 : 0);
    int kc = k0 & 511;
    int flip = (k0 >= 512) ? 4095 : 0;
    #pragma unroll
    for (int it=0; it<4; ++it){
      int row = it*32 + wv*8 + lrow;
      int sr = (mt*128 + row) ^ flip;        // flip s within batch for bwd half
      gload_lds16(Abase + (size_t)sr*512 + kc + slotp*8,
                  As + (it*32 + wv*8)*64);
    }
    #pragma unroll
    for (int it=0; it<2; ++it){
      int row = it*32 + wv*8 + lrow;
      gload_lds16(Wf + (size_t)(n0 + row)*1024 + k0 + slotp*8,
                  Bs + (it*32 + wv*8)*64);
    }
    __syncthreads();
    #pragma unroll
    for (int kk=0; kk<2; ++kk){
      int kslot = kk*4 + (lane >> 4);
      u32x4 af[2];
      #pragma unroll
      for (int mf=0; mf<2; ++mf){
        int row = wv*32 + mf*16 + (lane & 15);
        af[mf] = *(const u32x4*)(As + row*64 + ((kslot ^ (row&7))<<3));
      }
      #pragma unroll
      for (int nf=0; nf<4; ++nf){
        int row = nf*16 + (lane & 15);
        u32x4 bv = *(const u32x4*)(Bs + row*64 + ((kslot ^ (row&7))<<3));
        #pragma unroll
        for (int mf=0; mf<2; ++mf) mfma_bf16(acc[mf][nf], af[mf], bv);
      }
    }
    __syncthreads();
  }
  mfma_fence();

  #pragma unroll
  for (int nf=0; nf<4; ++nf){
    int col = n0 + nf*16 + (lane & 15);
    float bias = fb[col];
    #pragma unroll
    for (int mf=0; mf<2; ++mf){
      int rb = mt*128 + wv*32 + mf*16 + ((lane>>4)<<2);
      #pragma unroll
      for (int r=0; r<4; ++r)
        outp[(size_t)(rb + r)*512 + col] = acc[mf][nf][r] + bias;
    }
  }
}

// ---------------- launch ----------------

extern "C" void kernel_launch(void* const* d_in, const int* in_sizes, int n_in,
                              void* d_out, int out_size, void* d_ws, size_t ws_size,
                              hipStream_t stream)
{
  (void)in_sizes; (void)n_in; (void)out_size;
  const float* x   = (const float*)d_in[0];
  const float* wzf = (const float*)d_in[1];
  const float* bzf = (const float*)d_in[2];
  const float* whf = (const float*)d_in[3];
  const float* bhf = (const float*)d_in[4];
  const float* wzb = (const float*)d_in[5];
  const float* bzb = (const float*)d_in[6];
  const float* whb = (const float*)d_in[7];
  const float* bhb = (const float*)d_in[8];
  const float* fw  = (const float*)d_in[9];
  const float* fbb = (const float*)d_in[10];
  const float* lng = (const float*)d_in[11];
  const float* lnb = (const float*)d_in[12];
  float* outp = (float*)d_out;

  // Pick the largest per-direction batch-group count SG that fits ws_size.
  const size_t WbfB = (size_t)16*512*512*2;        // 8 MiB
  const size_t WfbB = (size_t)512*1024*2;          // 1 MiB
  const size_t XB   = (size_t)2*BSROWS*512*2;      // 64 MiB
  const size_t aggB = (size_t)4096*NCHUNK*4;       // 512 KiB (max CG)
  int SG = 8;
  for (int c = 1; c <= 8; c <<= 1){
    size_t need = WbfB + WfbB + XB + 3*aggB
                + ((size_t)BSROWS/c)*512*4          // PH
                + 1024;
    if (need <= ws_size){ SG = c; break; }
  }
  const int R  = BSROWS / SG;      // rows per group
  const int NBg = NB / SG;         // batches per group
  const int CG = NBg * 512;        // scan chains per group
  const int Mtiles = R / 128;

  char* ws = (char*)d_ws;
  size_t o = 0;
  unsigned short* Wbf = (unsigned short*)(ws + o); o += WbfB;
  unsigned short* Wfb = (unsigned short*)(ws + o); o += WfbB;
  unsigned short* X   = (unsigned short*)(ws + o); o += XB;
  unsigned int*   PH  = (unsigned int*)  (ws + o); o += (size_t)R*512*4;
  float* Aagg = (float*)(ws + o); o += aggB;
  float* Bagg = (float*)(ws + o); o += aggB;
  float* Hin  = (float*)(ws + o); o += aggB;

  prep_w <<<2048, 256, 0, stream>>>(wzf, whf, wzb, whb, Wbf);
  prep_fw<<<256,  256, 0, stream>>>(fw, Wfb);
  prep_x <<<8192, 256, 0, stream>>>(x, X);   // dir-0 half only

  // Helper macro: one (gemm -> combine -> recon) chain.
  #define CHAIN(Xin_, Xg_, WzP_, WhP_, bzP_, bhP_, flip_, resid_)            \
    do {                                                                     \
      gate_gemm_scan<<<Mtiles*8, 256, 0, stream>>>(Xin_, WzP_, WhP_,         \
          bzP_, bhP_, PH, Aagg, Bagg, Mtiles, CG, flip_);                    \
      scan_p2 <<<CG/256, 256, 0, stream>>>(Aagg, Bagg, Hin, CG);             \
      recon_ln<<<R/4,    256, 0, stream>>>(PH, Hin, Xg_, lng, lnb, resid_, CG); \
    } while (0)

  // Phase 1: dir-1 layer 0 consumes the PRISTINE dir-0 panel (row-flipped)
  // before dir-0's in-place processing overwrites it.
  for (int g = 0; g < SG; ++g){
    unsigned short* X0g = X + (size_t)g*R*512;                       // dir-0 group
    unsigned short* X1g = X + ((size_t)BSROWS + (size_t)g*R)*512;    // dir-1 group
    const unsigned short* Wz = Wbf + ((size_t)((1*4 + 0)*2 + 0))*(512*512);
    const unsigned short* Wh = Wbf + ((size_t)((1*4 + 0)*2 + 1))*(512*512);
    CHAIN(X0g, X1g, Wz, Wh, bzb + 0*512, bhb + 0*512, 4095, 0);
  }
  // Phase 2: dir-0 layers 0..3 (in place).
  for (int g = 0; g < SG; ++g){
    unsigned short* X0g = X + (size_t)g*R*512;
    for (int l = 0; l < NLAYER; ++l){
      const unsigned short* Wz = Wbf + ((size_t)((0*4 + l)*2 + 0))*(512*512);
      const unsigned short* Wh = Wbf + ((size_t)((0*4 + l)*2 + 1))*(512*512);
      CHAIN(X0g, X0g, Wz, Wh, bzf + l*512, bhf + l*512, 0, l > 0 ? 1 : 0);
    }
  }
  // Phase 3: dir-1 layers 1..3 (in place).
  for (int g = 0; g < SG; ++g){
    unsigned short* X1g = X + ((size_t)BSROWS + (size_t)g*R)*512;
    for (int l = 1; l < NLAYER; ++l){
      const unsigned short* Wz = Wbf + ((size_t)((1*4 + l)*2 + 0))*(512*512);
      const unsigned short* Wh = Wbf + ((size_t)((1*4 + l)*2 + 1))*(512*512);
      CHAIN(X1g, X1g, Wz, Wh, bzb + l*512, bhb + l*512, 0, 1);
    }
  }
  #undef CHAIN

  fusion_gemm<<<2048, 256, 0, stream>>>(X, Wfb, fbb, outp);
}

// Round 9
// 665.206 us; speedup vs baseline: 1.1760x; 1.0535x over previous
//
#include <hip/hip_runtime.h>

#define HID 512
#define SLEN 4096
#define NB 8
#define BSROWS (NB*SLEN)     // 32768 rows per direction
#define NLAYER 4
#define CHUNKT 128
#define NCHUNK 32
#define MTPD 256             // M-tiles per direction (BSROWS/128)
#define CGALL 8192           // scan chains total (2 dirs * 8 batches * 512)

typedef float f32x4 __attribute__((ext_vector_type(4)));
typedef unsigned int u32x4 __attribute__((ext_vector_type(4)));

typedef const __attribute__((address_space(1))) unsigned int* gas_u32p;
typedef __attribute__((address_space(3))) unsigned int* las_u32p;

__device__ __forceinline__ float bf2f(unsigned short u){
  union { unsigned int i; float f; } v; v.i = ((unsigned int)u) << 16; return v.f;
}
__device__ __forceinline__ unsigned short f2bf(float f){
  union { float f; unsigned int i; } v; v.f = f;
  unsigned int u = v.i;
  u = u + 0x7fffu + ((u >> 16) & 1u);
  return (unsigned short)(u >> 16);
}
__device__ __forceinline__ void mfma_bf16(f32x4& acc, u32x4 a, u32x4 b){
  asm("v_mfma_f32_16x16x32_bf16 %0, %1, %2, %0" : "+v"(acc) : "v"(a), "v"(b));
}
// MFMA D-write -> VALU read hazard fence (inline asm is opaque to the
// hazard recognizer; CDNA has no HW interlock here).
__device__ __forceinline__ void mfma_fence(){
  __builtin_amdgcn_sched_barrier(0);
  asm volatile("s_nop 7\n\ts_nop 7\n\ts_nop 7\n\ts_nop 7");
  __builtin_amdgcn_sched_barrier(0);
}
__device__ __forceinline__ void decode_ab(unsigned int v, float& a, float& b){
  a = (float)(v & 0xffffu) * (1.f/65535.f);
  b = fmaf((float)(v >> 16), 2.f/65535.f, -1.f);
}
__device__ __forceinline__ void gload_lds16(const unsigned short* g, unsigned short* l){
  __builtin_amdgcn_global_load_lds((gas_u32p)(const void*)g, (las_u32p)(void*)l, 16, 0, 0);
}
// scan-LDS index with bank-conflict-breaking band swizzle
__device__ __forceinline__ int scidx(int row, int col){
  return row*64 + (col ^ (((row>>2)&3)<<4));
}

// ---------------- prep kernels ----------------

__global__ __launch_bounds__(256) void prep_w(
    const float* __restrict__ wzf, const float* __restrict__ whf,
    const float* __restrict__ wzb, const float* __restrict__ whb,
    unsigned short* __restrict__ wbf)
{
  int idx = blockIdx.x*256 + threadIdx.x;   // 524288 total
  int i8  = idx & 63;
  int o   = (idx >> 6) & 511;
  int m   = (idx >> 15) & 1;
  int l   = (idx >> 16) & 3;
  int dir = idx >> 18;
  const float* src = dir ? (m ? whb : wzb) : (m ? whf : wzf);
  const float* p = src + ((size_t)(l*512 + o)*512 + i8*8);
  float4 v0 = *(const float4*)p;
  float4 v1 = *(const float4*)(p+4);
  unsigned short* q = wbf + ((((size_t)(dir*4 + l)*2 + m)*512 + o)*512 + i8*8);
  u32x4 outv;
  outv[0] = (unsigned)f2bf(v0.x) | ((unsigned)f2bf(v0.y)<<16);
  outv[1] = (unsigned)f2bf(v0.z) | ((unsigned)f2bf(v0.w)<<16);
  outv[2] = (unsigned)f2bf(v1.x) | ((unsigned)f2bf(v1.y)<<16);
  outv[3] = (unsigned)f2bf(v1.z) | ((unsigned)f2bf(v1.w)<<16);
  *(u32x4*)q = outv;
}

__global__ __launch_bounds__(256) void prep_fw(
    const float* __restrict__ fw, unsigned short* __restrict__ outw)
{
  int idx = blockIdx.x*256 + threadIdx.x;   // 65536
  const float* p = fw + (size_t)idx*8;
  float4 v0 = *(const float4*)p;
  float4 v1 = *(const float4*)(p+4);
  u32x4 outv;
  outv[0] = (unsigned)f2bf(v0.x) | ((unsigned)f2bf(v0.y)<<16);
  outv[1] = (unsigned)f2bf(v0.z) | ((unsigned)f2bf(v0.w)<<16);
  outv[2] = (unsigned)f2bf(v1.x) | ((unsigned)f2bf(v1.y)<<16);
  outv[3] = (unsigned)f2bf(v1.z) | ((unsigned)f2bf(v1.w)<<16);
  *(u32x4*)(outw + (size_t)idx*8) = outv;
}

// forward direction only; l=0 gate reads this for BOTH dirs (dir1 row-flipped).
__global__ __launch_bounds__(256) void prep_x(
    const float* __restrict__ x, unsigned short* __restrict__ X0)
{
  int idx = blockIdx.x*256 + threadIdx.x;   // 2097152
  int j8  = idx & 63;
  int s   = (idx >> 6) & 4095;
  int b   = idx >> 18;
  const float* p = x + ((size_t)(b*SLEN + s)*512 + j8*8);
  float4 v0 = *(const float4*)p;
  float4 v1 = *(const float4*)(p+4);
  u32x4 outv;
  outv[0] = (unsigned)f2bf(v0.x) | ((unsigned)f2bf(v0.y)<<16);
  outv[1] = (unsigned)f2bf(v0.z) | ((unsigned)f2bf(v0.w)<<16);
  outv[2] = (unsigned)f2bf(v1.x) | ((unsigned)f2bf(v1.y)<<16);
  outv[3] = (unsigned)f2bf(v1.z) | ((unsigned)f2bf(v1.w)<<16);
  *(u32x4*)(X0 + ((size_t)(b*SLEN + s)*512 + j8*8)) = outv;
}

// ---------------- gate GEMM + in-block chunk scan (both dirs, one dispatch) ----
// Grid: 4096 blocks = 2 dirs x (256 mt x 8 nt). Block internals are the r7
// proven 4-wave 128x64 kernel, verbatim. dir decoded from blockIdx.

__global__ __launch_bounds__(256) void gate_gemm_scan(
    const unsigned short* __restrict__ X,    // full [2*BSROWS][512] bf16
    const unsigned short* __restrict__ Wbf,  // [2][4][2][512][512] bf16
    const float* __restrict__ bzf, const float* __restrict__ bhf,
    const float* __restrict__ bzb, const float* __restrict__ bhb,
    unsigned int* __restrict__ PH0,          // dir0 [BSROWS][512] packed (P,h')
    unsigned int* __restrict__ PH1,          // dir1 (lives in d_out)
    float* __restrict__ Aagg, float* __restrict__ Bagg,
    int layer, int xoff1, int flip1)         // l==0: xoff1=0, flip1=4095
{
  __shared__ __align__(16) unsigned char smem[32768 + 2048];
  unsigned short* As  = (unsigned short*)smem;              // [128][64] bf16
  unsigned short* Bzs = (unsigned short*)(smem + 16384);    // [64][64]
  unsigned short* Bhs = (unsigned short*)(smem + 24576);    // [64][64]
  unsigned int*   SC  = (unsigned int*)smem;                // [128][64] u32 (alias)
  float* SegP = (float*)(smem + 32768);                     // [4][64]
  float* SegH = (float*)(smem + 32768 + 1024);              // [4][64]

  int hw = blockIdx.x;
  int dir = hw >= (MTPD*8);
  int hwl = hw - dir*(MTPD*8);
  int lg = (hwl & 7)*MTPD + (hwl >> 3);     // XCD-chunked swizzle within half
  int nt  = lg & 7;
  int mt  = lg >> 3;                        // 0..255

  const unsigned short* Xp = X + (size_t)(dir ? xoff1 : 0)*512;
  const int flip = dir ? flip1 : 0;
  const unsigned short* Wz = Wbf + ((size_t)((dir*4 + layer)*2 + 0))*(512*512);
  const unsigned short* Wh = Wbf + ((size_t)((dir*4 + layer)*2 + 1))*(512*512);
  const float* bzp = (dir ? bzb : bzf) + layer*512;
  const float* bhp = (dir ? bhb : bhf) + layer*512;
  unsigned int* PHp = dir ? PH1 : PH0;

  const int tid = threadIdx.x;
  const int lane = tid & 63;
  const int wv = tid >> 6;
  const int n0 = nt*64;
  const int slot = tid & 7;
  const int rowb = tid >> 3;

  f32x4 accz[2][4], acch[2][4];
  #pragma unroll
  for (int i=0;i<2;++i)
    #pragma unroll
    for (int j=0;j<4;++j){ accz[i][j] = (f32x4)(0.f); acch[i][j] = (f32x4)(0.f); }

  for (int ks=0; ks<8; ++ks){
    int k0 = ks*64;
    #pragma unroll
    for (int it=0; it<4; ++it){
      int row = rowb + it*32;
      int sr = (mt*128 + row) ^ flip;     // batch-local row flip (dir1, layer0)
      u32x4 v = *(const u32x4*)(Xp + (size_t)sr*512 + k0 + slot*8);
      *(u32x4*)(As + row*64 + ((slot ^ (row&7))<<3)) = v;
    }
    #pragma unroll
    for (int it=0; it<2; ++it){
      int row = rowb + it*32;
      u32x4 vz = *(const u32x4*)(Wz + (size_t)(n0+row)*512 + k0 + slot*8);
      *(u32x4*)(Bzs + row*64 + ((slot ^ (row&7))<<3)) = vz;
      u32x4 vh = *(const u32x4*)(Wh + (size_t)(n0+row)*512 + k0 + slot*8);
      *(u32x4*)(Bhs + row*64 + ((slot ^ (row&7))<<3)) = vh;
    }
    __syncthreads();
    #pragma unroll
    for (int kk=0; kk<2; ++kk){
      int kslot = kk*4 + (lane >> 4);
      u32x4 af[2];
      #pragma unroll
      for (int mf=0; mf<2; ++mf){
        int row = wv*32 + mf*16 + (lane & 15);
        af[mf] = *(const u32x4*)(As + row*64 + ((kslot ^ (row&7))<<3));
      }
      #pragma unroll
      for (int nf=0; nf<4; ++nf){
        int row = nf*16 + (lane & 15);
        u32x4 bz = *(const u32x4*)(Bzs + row*64 + ((kslot ^ (row&7))<<3));
        u32x4 bh = *(const u32x4*)(Bhs + row*64 + ((kslot ^ (row&7))<<3));
        #pragma unroll
        for (int mf=0; mf<2; ++mf){
          mfma_bf16(accz[mf][nf], af[mf], bz);
          mfma_bf16(acch[mf][nf], af[mf], bh);
        }
      }
    }
    __syncthreads();
  }
  mfma_fence();

  // ---- epilogue: gates -> packed fixed-point (a,b) into LDS (band-swizzled) ----
  #pragma unroll
  for (int nf=0; nf<4; ++nf){
    int colL = nf*16 + (lane & 15);
    float bz = bzp[n0 + colL];
    float bh = bhp[n0 + colL];
    #pragma unroll
    for (int mf=0; mf<2; ++mf){
      int rloc = wv*32 + mf*16 + ((lane>>4)<<2);
      #pragma unroll
      for (int r=0; r<4; ++r){
        float zp = accz[mf][nf][r] + bz;
        float hp = acch[mf][nf][r] + bh;
        float sg = 1.f/(1.f + __expf(-zp));
        float th = 1.f - 2.f/(1.f + __expf(2.f*hp));
        float a = 1.f - sg;
        a = fminf(fmaxf(a, 1e-8f), 1.0f);   // ref clip hi = 1-1e-8, rounds to 1.0f
        float bv = sg*th;                    // |bv| < 1
        unsigned aq = (unsigned)fmaf(a, 65535.f, 0.5f);
        unsigned bq = (unsigned)fmaf(bv, 32767.5f, 32768.0f);
        SC[scidx(rloc + r, colL)] = aq | (bq << 16);
      }
    }
  }
  __syncthreads();

  // ---- pass 1: per-segment aggregates only (no LDS rewrite) ----
  const int col = tid & 63;
  const int seg = tid >> 6;       // == wave id, uniform per wave
  {
    float P = 1.f, Hl = 0.f;
    #pragma unroll 8
    for (int r=0; r<32; ++r){
      float a, b; decode_ab(SC[scidx(seg*32 + r, col)], a, b);
      Hl = fmaf(a, Hl, b);
      P *= a;
    }
    SegP[seg*64 + col] = P;
    SegH[seg*64 + col] = Hl;
  }
  __syncthreads();

  // ---- segment prefixes (<=3 serial combines, wave-uniform trip count) ----
  float Ppre = 1.f, Hpre = 0.f;
  for (int j=0; j<seg; ++j){
    Hpre = fmaf(SegP[j*64 + col], Hpre, SegH[j*64 + col]);
    Ppre *= SegP[j*64 + col];
  }

  // ---- pass 2: recompute local scan, fuse prefix, write (P,h') + aggregates ----
  const int rowbase = mt*128;
  float pl = 1.f, hl = 0.f;
  float Pg = 1.f, Hg = 0.f;
  #pragma unroll 8
  for (int r=0; r<32; ++r){
    int row = seg*32 + r;
    float a, b; decode_ab(SC[scidx(row, col)], a, b);
    hl = fmaf(a, hl, b);
    pl *= a;
    Pg = Ppre * pl;
    Hg = fmaf(pl, Hpre, hl);
    unsigned pq = (unsigned)fmaf(Pg, 65535.f, 0.5f);
    PHp[(size_t)(rowbase + row)*512 + n0 + col] = pq | ((unsigned)f2bf(Hg) << 16);
  }
  if (seg == 3){
    int chain = dir*4096 + (mt >> 5)*512 + n0 + col;   // (dir*8+b)*512 + h
    int c = mt & 31;                                   // chunk within sequence
    Aagg[c*CGALL + chain] = Pg;
    Bagg[c*CGALL + chain] = Hg;
  }
}

// ---------------- cross-chunk combine (tiny) ----------------

__global__ __launch_bounds__(256) void scan_p2(
    const float* __restrict__ Aagg, const float* __restrict__ Bagg,
    float* __restrict__ Hin)
{
  int chain = blockIdx.x*256 + threadIdx.x;  // CGALL threads
  float hv = 0.f;
  #pragma unroll
  for (int c=0; c<NCHUNK; ++c){
    Hin[c*CGALL + chain] = hv;
    hv = fmaf(Aagg[c*CGALL + chain], hv, Bagg[c*CGALL + chain]);
  }
}

// ---------------- h reconstruction + residual + LayerNorm (in-place X) ----------------
// One dispatch covers both dirs (65536 tokens); PH split across two buffers.

__global__ __launch_bounds__(256) void recon_ln(
    const unsigned int* __restrict__ PH0,
    const unsigned int* __restrict__ PH1,
    const float* __restrict__ Hin,           // [32][CGALL]
    unsigned short* __restrict__ Xio,        // full [2*BSROWS][512] bf16 in/out
    const float* __restrict__ g, const float* __restrict__ bta, int resid)
{
  int token = blockIdx.x*4 + (threadIdx.x >> 6);   // 0..65535
  int lane = threadIdx.x & 63;
  int dir  = token >> 15;
  int tloc = token & (BSROWS-1);
  const unsigned int* PHp = dir ? PH1 : PH0;
  size_t pbase = (size_t)tloc*512 + lane*8;
  u32x4 p0 = *(const u32x4*)(PHp + pbase);
  u32x4 p1 = *(const u32x4*)(PHp + pbase + 4);
  int c = (tloc >> 7) & 31;
  const float* hin = Hin + (size_t)c*CGALL + (token >> 12)*512 + lane*8;
  f32x4 h0 = *(const f32x4*)hin;
  f32x4 h1 = *(const f32x4*)(hin + 4);
  float v[8];
  #pragma unroll
  for (int j=0; j<4; ++j){
    v[j]   = fmaf((float)(p0[j] & 0xffffu)*(1.f/65535.f), h0[j], bf2f((unsigned short)(p0[j] >> 16)));
    v[4+j] = fmaf((float)(p1[j] & 0xffffu)*(1.f/65535.f), h1[j], bf2f((unsigned short)(p1[j] >> 16)));
  }
  size_t base = (size_t)token*512 + lane*8;
  if (resid){
    u32x4 xv = *(const u32x4*)(Xio + base);
    #pragma unroll
    for (int w=0; w<4; ++w){
      v[2*w]   += bf2f((unsigned short)(xv[w] & 0xffffu));
      v[2*w+1] += bf2f((unsigned short)(xv[w] >> 16));
    }
  }
  float s = 0.f, s2 = 0.f;
  #pragma unroll
  for (int j=0; j<8; ++j){ s += v[j]; s2 += v[j]*v[j]; }
  #pragma unroll
  for (int o=1; o<64; o<<=1){ s += __shfl_xor(s, o, 64); s2 += __shfl_xor(s2, o, 64); }
  float mu = s * (1.f/512.f);
  float var = s2 * (1.f/512.f) - mu*mu;
  float inv = rsqrtf(var + 1e-5f);
  float4 g0 = *(const float4*)(g + lane*8);
  float4 g1 = *(const float4*)(g + lane*8 + 4);
  float4 b0 = *(const float4*)(bta + lane*8);
  float4 b1 = *(const float4*)(bta + lane*8 + 4);
  float gg[8]  = {g0.x,g0.y,g0.z,g0.w,g1.x,g1.y,g1.z,g1.w};
  float bbv[8] = {b0.x,b0.y,b0.z,b0.w,b1.x,b1.y,b1.z,b1.w};
  u32x4 outv;
  #pragma unroll
  for (int w=0; w<4; ++w){
    float y0 = (v[2*w]   - mu)*inv*gg[2*w]   + bbv[2*w];
    float y1 = (v[2*w+1] - mu)*inv*gg[2*w+1] + bbv[2*w+1];
    outv[w] = (unsigned)f2bf(y0) | ((unsigned)f2bf(y1) << 16);
  }
  *(u32x4*)(Xio + base) = outv;
}

// ---------------- fusion GEMM: out = [fwd, flip(bwd)] @ Wf^T + fb ----------------

__global__ __launch_bounds__(256) void fusion_gemm(
    const unsigned short* __restrict__ Xf,   // [2*BSROWS][512] final LN outputs
    const unsigned short* __restrict__ Wf,   // [512][1024] bf16
    const float* __restrict__ fb,
    float* __restrict__ outp)
{
  __shared__ __align__(16) unsigned short As[128*64];
  __shared__ __align__(16) unsigned short Bs[64*64];

  int hw = blockIdx.x;
  int lg = (hw & 7)*256 + (hw >> 3);   // 2048 blocks
  int nt = lg & 7;
  int mt = lg >> 3;                    // 0..255

  const int tid = threadIdx.x;
  const int lane = tid & 63;
  const int wv = tid >> 6;
  const int n0 = nt*64;
  const int lrow  = lane >> 3;
  const int slotp = (lane & 7) ^ (lrow & 7);

  f32x4 acc[2][4];
  #pragma unroll
  for (int i=0;i<2;++i)
    #pragma unroll
    for (int j=0;j<4;++j) acc[i][j] = (f32x4)(0.f);

  for (int ks=0; ks<16; ++ks){
    int k0 = ks*64;
    const unsigned short* Abase = Xf + ((k0 >= 512) ? (size_t)BSROWS*512 : 0);
    int kc = k0 & 511;
    int flip = (k0 >= 512) ? 4095 : 0;
    #pragma unroll
    for (int it=0; it<4; ++it){
      int row = it*32 + wv*8 + lrow;
      int sr = (mt*128 + row) ^ flip;        // flip s within batch for bwd half
      gload_lds16(Abase + (size_t)sr*512 + kc + slotp*8,
                  As + (it*32 + wv*8)*64);
    }
    #pragma unroll
    for (int it=0; it<2; ++it){
      int row = it*32 + wv*8 + lrow;
      gload_lds16(Wf + (size_t)(n0 + row)*1024 + k0 + slotp*8,
                  Bs + (it*32 + wv*8)*64);
    }
    __syncthreads();
    #pragma unroll
    for (int kk=0; kk<2; ++kk){
      int kslot = kk*4 + (lane >> 4);
      u32x4 af[2];
      #pragma unroll
      for (int mf=0; mf<2; ++mf){
        int row = wv*32 + mf*16 + (lane & 15);
        af[mf] = *(const u32x4*)(As + row*64 + ((kslot ^ (row&7))<<3));
      }
      #pragma unroll
      for (int nf=0; nf<4; ++nf){
        int row = nf*16 + (lane & 15);
        u32x4 bv = *(const u32x4*)(Bs + row*64 + ((kslot ^ (row&7))<<3));
        #pragma unroll
        for (int mf=0; mf<2; ++mf) mfma_bf16(acc[mf][nf], af[mf], bv);
      }
    }
    __syncthreads();
  }
  mfma_fence();

  #pragma unroll
  for (int nf=0; nf<4; ++nf){
    int col = n0 + nf*16 + (lane & 15);
    float bias = fb[col];
    #pragma unroll
    for (int mf=0; mf<2; ++mf){
      int rb = mt*128 + wv*32 + mf*16 + ((lane>>4)<<2);
      #pragma unroll
      for (int r=0; r<4; ++r)
        outp[(size_t)(rb + r)*512 + col] = acc[mf][nf][r] + bias;
    }
  }
}

// ---------------- launch ----------------

extern "C" void kernel_launch(void* const* d_in, const int* in_sizes, int n_in,
                              void* d_out, int out_size, void* d_ws, size_t ws_size,
                              hipStream_t stream)
{
  (void)in_sizes; (void)n_in; (void)out_size; (void)ws_size;
  const float* x   = (const float*)d_in[0];
  const float* wzf = (const float*)d_in[1];
  const float* bzf = (const float*)d_in[2];
  const float* whf = (const float*)d_in[3];
  const float* bhf = (const float*)d_in[4];
  const float* wzb = (const float*)d_in[5];
  const float* bzb = (const float*)d_in[6];
  const float* whb = (const float*)d_in[7];
  const float* bhb = (const float*)d_in[8];
  const float* fw  = (const float*)d_in[9];
  const float* fbb = (const float*)d_in[10];
  const float* lng = (const float*)d_in[11];
  const float* lnb = (const float*)d_in[12];
  float* outp = (float*)d_out;

  // ws layout (~140 MiB; r2's profile proves ws >= ~171 MiB):
  char* ws = (char*)d_ws;
  size_t o = 0;
  unsigned short* Wbf = (unsigned short*)(ws + o); o += (size_t)16*512*512*2;   // 8 MiB
  unsigned short* Wfb = (unsigned short*)(ws + o); o += (size_t)512*1024*2;     // 1 MiB
  unsigned short* X   = (unsigned short*)(ws + o); o += (size_t)2*BSROWS*512*2; // 64 MiB
  unsigned int*   PH0 = (unsigned int*)  (ws + o); o += (size_t)BSROWS*512*4;   // 64 MiB
  float* Aagg = (float*)(ws + o); o += (size_t)CGALL*NCHUNK*4;                  // 1 MiB
  float* Bagg = (float*)(ws + o); o += (size_t)CGALL*NCHUNK*4;
  float* Hin  = (float*)(ws + o); o += (size_t)CGALL*NCHUNK*4;
  // dir-1 PH lives in d_out (exactly BSROWS*512*4 = 64 MiB); fully
  // overwritten before any read each call; fusion writes final out last.
  unsigned int* PH1 = (unsigned int*)d_out;

  prep_w <<<2048, 256, 0, stream>>>(wzf, whf, wzb, whb, Wbf);
  prep_fw<<<256,  256, 0, stream>>>(fw, Wfb);
  prep_x <<<8192, 256, 0, stream>>>(x, X);   // dir-0 half only

  for (int l = 0; l < NLAYER; ++l){
    // l==0: both dirs read the pristine dir-0 panel (dir1 row-flipped).
    int xoff1 = (l == 0) ? 0 : BSROWS;
    int flip1 = (l == 0) ? 4095 : 0;
    gate_gemm_scan<<<4096, 256, 0, stream>>>(X, Wbf, bzf, bhf, bzb, bhb,
                                             PH0, PH1, Aagg, Bagg, l, xoff1, flip1);
    scan_p2 <<<CGALL/256, 256, 0, stream>>>(Aagg, Bagg, Hin);
    recon_ln<<<16384, 256, 0, stream>>>(PH0, PH1, Hin, X, lng, lnb, l > 0 ? 1 : 0);
  }

  fusion_gemm<<<2048, 256, 0, stream>>>(X, Wfb, fbb, outp);
}

// Round 10
// 609.459 us; speedup vs baseline: 1.2836x; 1.0915x over previous
//
#include <hip/hip_runtime.h>

#define HID 512
#define SLEN 4096
#define NB 8
#define BSROWS (NB*SLEN)     // 32768 rows per direction
#define NLAYER 4
#define CHUNKT 128
#define NCHUNK 32
#define MTPD 256             // M-tiles per direction (BSROWS/128)
#define CGALL 8192           // scan chains total (2 dirs * 8 batches * 512)

typedef float f32x4 __attribute__((ext_vector_type(4)));
typedef unsigned int u32x4 __attribute__((ext_vector_type(4)));

typedef const __attribute__((address_space(1))) unsigned int* gas_u32p;
typedef __attribute__((address_space(3))) unsigned int* las_u32p;

__device__ __forceinline__ float bf2f(unsigned short u){
  union { unsigned int i; float f; } v; v.i = ((unsigned int)u) << 16; return v.f;
}
__device__ __forceinline__ unsigned short f2bf(float f){
  union { float f; unsigned int i; } v; v.f = f;
  unsigned int u = v.i;
  u = u + 0x7fffu + ((u >> 16) & 1u);
  return (unsigned short)(u >> 16);
}
__device__ __forceinline__ void mfma_bf16(f32x4& acc, u32x4 a, u32x4 b){
  asm("v_mfma_f32_16x16x32_bf16 %0, %1, %2, %0" : "+v"(acc) : "v"(a), "v"(b));
}
// MFMA D-write -> VALU read hazard fence (inline asm is opaque to the
// hazard recognizer; CDNA has no HW interlock here).
__device__ __forceinline__ void mfma_fence(){
  __builtin_amdgcn_sched_barrier(0);
  asm volatile("s_nop 7\n\ts_nop 7\n\ts_nop 7\n\ts_nop 7");
  __builtin_amdgcn_sched_barrier(0);
}
__device__ __forceinline__ void decode_ab(unsigned int v, float& a, float& b){
  a = (float)(v & 0xffffu) * (1.f/65535.f);
  b = fmaf((float)(v >> 16), 2.f/65535.f, -1.f);
}
__device__ __forceinline__ void gload_lds16(const unsigned short* g, unsigned short* l){
  __builtin_amdgcn_global_load_lds((gas_u32p)(const void*)g, (las_u32p)(void*)l, 16, 0, 0);
}
// scan-LDS index with bank-conflict-breaking band swizzle
__device__ __forceinline__ int scidx(int row, int col){
  return row*64 + (col ^ (((row>>2)&3)<<4));
}

// ---------------- prep kernels ----------------

__global__ __launch_bounds__(256) void prep_w(
    const float* __restrict__ wzf, const float* __restrict__ whf,
    const float* __restrict__ wzb, const float* __restrict__ whb,
    unsigned short* __restrict__ wbf)
{
  int idx = blockIdx.x*256 + threadIdx.x;   // 524288 total
  int i8  = idx & 63;
  int o   = (idx >> 6) & 511;
  int m   = (idx >> 15) & 1;
  int l   = (idx >> 16) & 3;
  int dir = idx >> 18;
  const float* src = dir ? (m ? whb : wzb) : (m ? whf : wzf);
  const float* p = src + ((size_t)(l*512 + o)*512 + i8*8);
  float4 v0 = *(const float4*)p;
  float4 v1 = *(const float4*)(p+4);
  unsigned short* q = wbf + ((((size_t)(dir*4 + l)*2 + m)*512 + o)*512 + i8*8);
  u32x4 outv;
  outv[0] = (unsigned)f2bf(v0.x) | ((unsigned)f2bf(v0.y)<<16);
  outv[1] = (unsigned)f2bf(v0.z) | ((unsigned)f2bf(v0.w)<<16);
  outv[2] = (unsigned)f2bf(v1.x) | ((unsigned)f2bf(v1.y)<<16);
  outv[3] = (unsigned)f2bf(v1.z) | ((unsigned)f2bf(v1.w)<<16);
  *(u32x4*)q = outv;
}

__global__ __launch_bounds__(256) void prep_fw(
    const float* __restrict__ fw, unsigned short* __restrict__ outw)
{
  int idx = blockIdx.x*256 + threadIdx.x;   // 65536
  const float* p = fw + (size_t)idx*8;
  float4 v0 = *(const float4*)p;
  float4 v1 = *(const float4*)(p+4);
  u32x4 outv;
  outv[0] = (unsigned)f2bf(v0.x) | ((unsigned)f2bf(v0.y)<<16);
  outv[1] = (unsigned)f2bf(v0.z) | ((unsigned)f2bf(v0.w)<<16);
  outv[2] = (unsigned)f2bf(v1.x) | ((unsigned)f2bf(v1.y)<<16);
  outv[3] = (unsigned)f2bf(v1.z) | ((unsigned)f2bf(v1.w)<<16);
  *(u32x4*)(outw + (size_t)idx*8) = outv;
}

// forward direction only; l=0 gate reads this for BOTH dirs (dir1 row-flipped).
__global__ __launch_bounds__(256) void prep_x(
    const float* __restrict__ x, unsigned short* __restrict__ X0)
{
  int idx = blockIdx.x*256 + threadIdx.x;   // 2097152
  int j8  = idx & 63;
  int s   = (idx >> 6) & 4095;
  int b   = idx >> 18;
  const float* p = x + ((size_t)(b*SLEN + s)*512 + j8*8);
  float4 v0 = *(const float4*)p;
  float4 v1 = *(const float4*)(p+4);
  u32x4 outv;
  outv[0] = (unsigned)f2bf(v0.x) | ((unsigned)f2bf(v0.y)<<16);
  outv[1] = (unsigned)f2bf(v0.z) | ((unsigned)f2bf(v0.w)<<16);
  outv[2] = (unsigned)f2bf(v1.x) | ((unsigned)f2bf(v1.y)<<16);
  outv[3] = (unsigned)f2bf(v1.z) | ((unsigned)f2bf(v1.w)<<16);
  *(u32x4*)(X0 + ((size_t)(b*SLEN + s)*512 + j8*8)) = outv;
}

// ---------------- gate GEMM + in-block chunk scan (both dirs, one dispatch) ----
// Grid: 4096 blocks = 2 dirs x (256 mt x 8 nt). Block internals are the r7
// proven 4-wave 128x64 kernel; epilogue uses v_rcp/v_exp (1-ulp) instead of
// IEEE divide; pass1 caches decoded (a,b) in registers for pass2.

__global__ __launch_bounds__(256) void gate_gemm_scan(
    const unsigned short* __restrict__ X,    // full [2*BSROWS][512] bf16
    const unsigned short* __restrict__ Wbf,  // [2][4][2][512][512] bf16
    const float* __restrict__ bzf, const float* __restrict__ bhf,
    const float* __restrict__ bzb, const float* __restrict__ bhb,
    unsigned int* __restrict__ PH0,          // dir0 [BSROWS][512] packed (P,h')
    unsigned int* __restrict__ PH1,          // dir1 (lives in d_out)
    float* __restrict__ Aagg, float* __restrict__ Bagg,
    int layer, int xoff1, int flip1)         // l==0: xoff1=0, flip1=4095
{
  __shared__ __align__(16) unsigned char smem[32768 + 2048];
  unsigned short* As  = (unsigned short*)smem;              // [128][64] bf16
  unsigned short* Bzs = (unsigned short*)(smem + 16384);    // [64][64]
  unsigned short* Bhs = (unsigned short*)(smem + 24576);    // [64][64]
  unsigned int*   SC  = (unsigned int*)smem;                // [128][64] u32 (alias)
  float* SegP = (float*)(smem + 32768);                     // [4][64]
  float* SegH = (float*)(smem + 32768 + 1024);              // [4][64]

  int hw = blockIdx.x;
  int dir = hw >= (MTPD*8);
  int hwl = hw - dir*(MTPD*8);
  int lg = (hwl & 7)*MTPD + (hwl >> 3);     // XCD-chunked swizzle within half
  int nt  = lg & 7;
  int mt  = lg >> 3;                        // 0..255

  const unsigned short* Xp = X + (size_t)(dir ? xoff1 : 0)*512;
  const int flip = dir ? flip1 : 0;
  const unsigned short* Wz = Wbf + ((size_t)((dir*4 + layer)*2 + 0))*(512*512);
  const unsigned short* Wh = Wbf + ((size_t)((dir*4 + layer)*2 + 1))*(512*512);
  const float* bzp = (dir ? bzb : bzf) + layer*512;
  const float* bhp = (dir ? bhb : bhf) + layer*512;
  unsigned int* PHp = dir ? PH1 : PH0;

  const int tid = threadIdx.x;
  const int lane = tid & 63;
  const int wv = tid >> 6;
  const int n0 = nt*64;
  const int slot = tid & 7;
  const int rowb = tid >> 3;

  f32x4 accz[2][4], acch[2][4];
  #pragma unroll
  for (int i=0;i<2;++i)
    #pragma unroll
    for (int j=0;j<4;++j){ accz[i][j] = (f32x4)(0.f); acch[i][j] = (f32x4)(0.f); }

  for (int ks=0; ks<8; ++ks){
    int k0 = ks*64;
    #pragma unroll
    for (int it=0; it<4; ++it){
      int row = rowb + it*32;
      int sr = (mt*128 + row) ^ flip;     // batch-local row flip (dir1, layer0)
      u32x4 v = *(const u32x4*)(Xp + (size_t)sr*512 + k0 + slot*8);
      *(u32x4*)(As + row*64 + ((slot ^ (row&7))<<3)) = v;
    }
    #pragma unroll
    for (int it=0; it<2; ++it){
      int row = rowb + it*32;
      u32x4 vz = *(const u32x4*)(Wz + (size_t)(n0+row)*512 + k0 + slot*8);
      *(u32x4*)(Bzs + row*64 + ((slot ^ (row&7))<<3)) = vz;
      u32x4 vh = *(const u32x4*)(Wh + (size_t)(n0+row)*512 + k0 + slot*8);
      *(u32x4*)(Bhs + row*64 + ((slot ^ (row&7))<<3)) = vh;
    }
    __syncthreads();
    #pragma unroll
    for (int kk=0; kk<2; ++kk){
      int kslot = kk*4 + (lane >> 4);
      u32x4 af[2];
      #pragma unroll
      for (int mf=0; mf<2; ++mf){
        int row = wv*32 + mf*16 + (lane & 15);
        af[mf] = *(const u32x4*)(As + row*64 + ((kslot ^ (row&7))<<3));
      }
      #pragma unroll
      for (int nf=0; nf<4; ++nf){
        int row = nf*16 + (lane & 15);
        u32x4 bz = *(const u32x4*)(Bzs + row*64 + ((kslot ^ (row&7))<<3));
        u32x4 bh = *(const u32x4*)(Bhs + row*64 + ((kslot ^ (row&7))<<3));
        #pragma unroll
        for (int mf=0; mf<2; ++mf){
          mfma_bf16(accz[mf][nf], af[mf], bz);
          mfma_bf16(acch[mf][nf], af[mf], bh);
        }
      }
    }
    __syncthreads();
  }
  mfma_fence();

  // ---- epilogue: gates -> packed fixed-point (a,b) into LDS (band-swizzled) ----
  // a = 1 - sigmoid(zp) = rcp(1 + exp2(log2e*zp)); th = 1 - 2*rcp(1+exp2(2*log2e*hp)).
  // v_rcp_f32 (1 ulp) replaces the IEEE divide sequence (~10 VALU each).
  const float C1 = 1.44269504f;   // log2(e)
  const float C2 = 2.88539008f;   // 2*log2(e)
  #pragma unroll
  for (int nf=0; nf<4; ++nf){
    int colL = nf*16 + (lane & 15);
    float bz = bzp[n0 + colL];
    float bh = bhp[n0 + colL];
    #pragma unroll
    for (int mf=0; mf<2; ++mf){
      int rloc = wv*32 + mf*16 + ((lane>>4)<<2);
      #pragma unroll
      for (int r=0; r<4; ++r){
        float zp = accz[mf][nf][r] + bz;
        float hp = acch[mf][nf][r] + bh;
        float a  = __builtin_amdgcn_rcpf(1.f + __builtin_amdgcn_exp2f(C1*zp));
        float th = fmaf(-2.f, __builtin_amdgcn_rcpf(1.f + __builtin_amdgcn_exp2f(C2*hp)), 1.f);
        a = fminf(fmaxf(a, 1e-8f), 1.0f);   // ref clip hi = 1-1e-8, rounds to 1.0f
        float bv = fmaf(-a, th, th);         // (1-a)*th = sigmoid(zp)*tanh(hp)
        unsigned aq = (unsigned)fmaf(a, 65535.f, 0.5f);
        unsigned bq = (unsigned)fmaf(bv, 32767.5f, 32768.0f);
        SC[scidx(rloc + r, colL)] = aq | (bq << 16);
      }
    }
  }
  __syncthreads();

  // ---- pass 1: decode once into registers, per-segment aggregates ----
  const int col = tid & 63;
  const int seg = tid >> 6;       // == wave id, uniform per wave
  float ar[32], br[32];           // fully-unrolled static indexing (no scratch)
  {
    float P = 1.f, Hl = 0.f;
    #pragma unroll
    for (int r=0; r<32; ++r){
      float a, b; decode_ab(SC[scidx(seg*32 + r, col)], a, b);
      ar[r] = a; br[r] = b;
      Hl = fmaf(a, Hl, b);
      P *= a;
    }
    SegP[seg*64 + col] = P;
    SegH[seg*64 + col] = Hl;
  }
  __syncthreads();

  // ---- segment prefixes (<=3 serial combines, wave-uniform trip count) ----
  float Ppre = 1.f, Hpre = 0.f;
  for (int j=0; j<seg; ++j){
    Hpre = fmaf(SegP[j*64 + col], Hpre, SegH[j*64 + col]);
    Ppre *= SegP[j*64 + col];
  }

  // ---- pass 2: rescan from registers, fuse prefix, write (P,h') + aggregates ----
  const int rowbase = mt*128;
  float pl = 1.f, hl = 0.f;
  float Pg = 1.f, Hg = 0.f;
  #pragma unroll
  for (int r=0; r<32; ++r){
    hl = fmaf(ar[r], hl, br[r]);
    pl *= ar[r];
    Pg = Ppre * pl;
    Hg = fmaf(pl, Hpre, hl);
    unsigned pq = (unsigned)fmaf(Pg, 65535.f, 0.5f);
    PHp[(size_t)(rowbase + seg*32 + r)*512 + n0 + col] = pq | ((unsigned)f2bf(Hg) << 16);
  }
  if (seg == 3){
    int chain = dir*4096 + (mt >> 5)*512 + n0 + col;   // (dir*8+b)*512 + h
    int c = mt & 31;                                   // chunk within sequence
    Aagg[c*CGALL + chain] = Pg;
    Bagg[c*CGALL + chain] = Hg;
  }
}

// ---------------- cross-chunk combine (tiny) ----------------

__global__ __launch_bounds__(256) void scan_p2(
    const float* __restrict__ Aagg, const float* __restrict__ Bagg,
    float* __restrict__ Hin)
{
  int chain = blockIdx.x*256 + threadIdx.x;  // CGALL threads
  float hv = 0.f;
  #pragma unroll
  for (int c=0; c<NCHUNK; ++c){
    Hin[c*CGALL + chain] = hv;
    hv = fmaf(Aagg[c*CGALL + chain], hv, Bagg[c*CGALL + chain]);
  }
}

// ---------------- h reconstruction + residual + LayerNorm (in-place X) ----------------
// One dispatch covers both dirs (65536 tokens); PH split across two buffers.

__global__ __launch_bounds__(256) void recon_ln(
    const unsigned int* __restrict__ PH0,
    const unsigned int* __restrict__ PH1,
    const float* __restrict__ Hin,           // [32][CGALL]
    unsigned short* __restrict__ Xio,        // full [2*BSROWS][512] bf16 in/out
    const float* __restrict__ g, const float* __restrict__ bta, int resid)
{
  int token = blockIdx.x*4 + (threadIdx.x >> 6);   // 0..65535
  int lane = threadIdx.x & 63;
  int dir  = token >> 15;
  int tloc = token & (BSROWS-1);
  const unsigned int* PHp = dir ? PH1 : PH0;
  size_t pbase = (size_t)tloc*512 + lane*8;
  u32x4 p0 = *(const u32x4*)(PHp + pbase);
  u32x4 p1 = *(const u32x4*)(PHp + pbase + 4);
  int c = (tloc >> 7) & 31;
  const float* hin = Hin + (size_t)c*CGALL + (token >> 12)*512 + lane*8;
  f32x4 h0 = *(const f32x4*)hin;
  f32x4 h1 = *(const f32x4*)(hin + 4);
  float v[8];
  #pragma unroll
  for (int j=0; j<4; ++j){
    v[j]   = fmaf((float)(p0[j] & 0xffffu)*(1.f/65535.f), h0[j], bf2f((unsigned short)(p0[j] >> 16)));
    v[4+j] = fmaf((float)(p1[j] & 0xffffu)*(1.f/65535.f), h1[j], bf2f((unsigned short)(p1[j] >> 16)));
  }
  size_t base = (size_t)token*512 + lane*8;
  if (resid){
    u32x4 xv = *(const u32x4*)(Xio + base);
    #pragma unroll
    for (int w=0; w<4; ++w){
      v[2*w]   += bf2f((unsigned short)(xv[w] & 0xffffu));
      v[2*w+1] += bf2f((unsigned short)(xv[w] >> 16));
    }
  }
  float s = 0.f, s2 = 0.f;
  #pragma unroll
  for (int j=0; j<8; ++j){ s += v[j]; s2 += v[j]*v[j]; }
  #pragma unroll
  for (int o=1; o<64; o<<=1){ s += __shfl_xor(s, o, 64); s2 += __shfl_xor(s2, o, 64); }
  float mu = s * (1.f/512.f);
  float var = s2 * (1.f/512.f) - mu*mu;
  float inv = rsqrtf(var + 1e-5f);
  float4 g0 = *(const float4*)(g + lane*8);
  float4 g1 = *(const float4*)(g + lane*8 + 4);
  float4 b0 = *(const float4*)(bta + lane*8);
  float4 b1 = *(const float4*)(bta + lane*8 + 4);
  float gg[8]  = {g0.x,g0.y,g0.z,g0.w,g1.x,g1.y,g1.z,g1.w};
  float bbv[8] = {b0.x,b0.y,b0.z,b0.w,b1.x,b1.y,b1.z,b1.w};
  u32x4 outv;
  #pragma unroll
  for (int w=0; w<4; ++w){
    float y0 = (v[2*w]   - mu)*inv*gg[2*w]   + bbv[2*w];
    float y1 = (v[2*w+1] - mu)*inv*gg[2*w+1] + bbv[2*w+1];
    outv[w] = (unsigned)f2bf(y0) | ((unsigned)f2bf(y1) << 16);
  }
  *(u32x4*)(Xio + base) = outv;
}

// ---------------- fusion GEMM: out = [fwd, flip(bwd)] @ Wf^T + fb ----------------

__global__ __launch_bounds__(256) void fusion_gemm(
    const unsigned short* __restrict__ Xf,   // [2*BSROWS][512] final LN outputs
    const unsigned short* __restrict__ Wf,   // [512][1024] bf16
    const float* __restrict__ fb,
    float* __restrict__ outp)
{
  __shared__ __align__(16) unsigned short As[128*64];
  __shared__ __align__(16) unsigned short Bs[64*64];

  int hw = blockIdx.x;
  int lg = (hw & 7)*256 + (hw >> 3);   // 2048 blocks
  int nt = lg & 7;
  int mt = lg >> 3;                    // 0..255

  const int tid = threadIdx.x;
  const int lane = tid & 63;
  const int wv = tid >> 6;
  const int n0 = nt*64;
  const int lrow  = lane >> 3;
  const int slotp = (lane & 7) ^ (lrow & 7);

  f32x4 acc[2][4];
  #pragma unroll
  for (int i=0;i<2;++i)
    #pragma unroll
    for (int j=0;j<4;++j) acc[i][j] = (f32x4)(0.f);

  for (int ks=0; ks<16; ++ks){
    int k0 = ks*64;
    const unsigned short* Abase = Xf + ((k0 >= 512) ? (size_t)BSROWS*512 : 0);
    int kc = k0 & 511;
    int flip = (k0 >= 512) ? 4095 : 0;
    #pragma unroll
    for (int it=0; it<4; ++it){
      int row = it*32 + wv*8 + lrow;
      int sr = (mt*128 + row) ^ flip;        // flip s within batch for bwd half
      gload_lds16(Abase + (size_t)sr*512 + kc + slotp*8,
                  As + (it*32 + wv*8)*64);
    }
    #pragma unroll
    for (int it=0; it<2; ++it){
      int row = it*32 + wv*8 + lrow;
      gload_lds16(Wf + (size_t)(n0 + row)*1024 + k0 + slotp*8,
                  Bs + (it*32 + wv*8)*64);
    }
    __syncthreads();
    #pragma unroll
    for (int kk=0; kk<2; ++kk){
      int kslot = kk*4 + (lane >> 4);
      u32x4 af[2];
      #pragma unroll
      for (int mf=0; mf<2; ++mf){
        int row = wv*32 + mf*16 + (lane & 15);
        af[mf] = *(const u32x4*)(As + row*64 + ((kslot ^ (row&7))<<3));
      }
      #pragma unroll
      for (int nf=0; nf<4; ++nf){
        int row = nf*16 + (lane & 15);
        u32x4 bv = *(const u32x4*)(Bs + row*64 + ((kslot ^ (row&7))<<3));
        #pragma unroll
        for (int mf=0; mf<2; ++mf) mfma_bf16(acc[mf][nf], af[mf], bv);
      }
    }
    __syncthreads();
  }
  mfma_fence();

  #pragma unroll
  for (int nf=0; nf<4; ++nf){
    int col = n0 + nf*16 + (lane & 15);
    float bias = fb[col];
    #pragma unroll
    for (int mf=0; mf<2; ++mf){
      int rb = mt*128 + wv*32 + mf*16 + ((lane>>4)<<2);
      #pragma unroll
      for (int r=0; r<4; ++r)
        outp[(size_t)(rb + r)*512 + col] = acc[mf][nf][r] + bias;
    }
  }
}

// ---------------- launch ----------------

extern "C" void kernel_launch(void* const* d_in, const int* in_sizes, int n_in,
                              void* d_out, int out_size, void* d_ws, size_t ws_size,
                              hipStream_t stream)
{
  (void)in_sizes; (void)n_in; (void)out_size; (void)ws_size;
  const float* x   = (const float*)d_in[0];
  const float* wzf = (const float*)d_in[1];
  const float* bzf = (const float*)d_in[2];
  const float* whf = (const float*)d_in[3];
  const float* bhf = (const float*)d_in[4];
  const float* wzb = (const float*)d_in[5];
  const float* bzb = (const float*)d_in[6];
  const float* whb = (const float*)d_in[7];
  const float* bhb = (const float*)d_in[8];
  const float* fw  = (const float*)d_in[9];
  const float* fbb = (const float*)d_in[10];
  const float* lng = (const float*)d_in[11];
  const float* lnb = (const float*)d_in[12];
  float* outp = (float*)d_out;

  // ws layout (~140 MiB; r2's profile proves ws >= ~171 MiB):
  char* ws = (char*)d_ws;
  size_t o = 0;
  unsigned short* Wbf = (unsigned short*)(ws + o); o += (size_t)16*512*512*2;   // 8 MiB
  unsigned short* Wfb = (unsigned short*)(ws + o); o += (size_t)512*1024*2;     // 1 MiB
  unsigned short* X   = (unsigned short*)(ws + o); o += (size_t)2*BSROWS*512*2; // 64 MiB
  unsigned int*   PH0 = (unsigned int*)  (ws + o); o += (size_t)BSROWS*512*4;   // 64 MiB
  float* Aagg = (float*)(ws + o); o += (size_t)CGALL*NCHUNK*4;                  // 1 MiB
  float* Bagg = (float*)(ws + o); o += (size_t)CGALL*NCHUNK*4;
  float* Hin  = (float*)(ws + o); o += (size_t)CGALL*NCHUNK*4;
  // dir-1 PH lives in d_out (exactly BSROWS*512*4 = 64 MiB); fully
  // overwritten before any read each call; fusion writes final out last.
  unsigned int* PH1 = (unsigned int*)d_out;

  prep_w <<<2048, 256, 0, stream>>>(wzf, whf, wzb, whb, Wbf);
  prep_fw<<<256,  256, 0, stream>>>(fw, Wfb);
  prep_x <<<8192, 256, 0, stream>>>(x, X);   // dir-0 half only

  for (int l = 0; l < NLAYER; ++l){
    // l==0: both dirs read the pristine dir-0 panel (dir1 row-flipped).
    int xoff1 = (l == 0) ? 0 : BSROWS;
    int flip1 = (l == 0) ? 4095 : 0;
    gate_gemm_scan<<<4096, 256, 0, stream>>>(X, Wbf, bzf, bhf, bzb, bhb,
                                             PH0, PH1, Aagg, Bagg, l, xoff1, flip1);
    scan_p2 <<<CGALL/256, 256, 0, stream>>>(Aagg, Bagg, Hin);
    recon_ln<<<16384, 256, 0, stream>>>(PH0, PH1, Hin, X, lng, lnb, l > 0 ? 1 : 0);
  }

  fusion_gemm<<<2048, 256, 0, stream>>>(X, Wfb, fbb, outp);
}